// Round 25
// baseline (7478.157 us; speedup 1.0000x reference)
//
#include <hip/hip_runtime.h>

#define NB 256
#define NT 32
#define ND 4096
#define NL 4096
#define NC 10
#define KC 512   // verified bit-exact: GEBP panels {512 x 8} per K=4096 matmul
#define BK 32    // k-slab per barrier pair; k-order within panel still ascending

// ---------------- state zero-init --------------------------------------------
__global__ void snn_zero(float* __restrict__ mem1, float* __restrict__ spkA,
                         float* __restrict__ mem2, float* __restrict__ spk2)
{
    const size_t i = (size_t)blockIdx.x * blockDim.x + threadIdx.x;
    if (i < (size_t)NB * NL) { mem1[i] = 0.f; spkA[i] = 0.f; }
    if (i < (size_t)NB * NC) { mem2[i] = 0.f; spk2[i] = 0.f; }
}

// ---------------- GEMM panel kernel (64x128, 4x4 micro, 512 thr, BK=32) ------
// Grid (4, 32, 16): bm, bn (128-col tiles), seg.
// seg 0..7  : panel p=seg   of x @ W1^T     (k in [512p, 512p+512))
// seg 8..15 : panel p=seg-8 of spkp @ Wr1^T
// Per output element: sequential ascending-k FMA chain from 0 (bit-exact).
// Role-split staging: waves 0-3 stage A (r22 split-k pattern, 2-way banks),
// waves 4-7 stage B (r23 row-per-thread pattern, 2-way banks).
// Each thread: 4x4 micro-tile -> 16 acc regs; worst-case prefetch 16 regs.
__global__ __launch_bounds__(512)
void gemm_panel(const float* __restrict__ x, const float* __restrict__ W1,
                const float* __restrict__ Wr1, const float* __restrict__ spkp,
                float* __restrict__ part, int t)
{
    __shared__ float As[BK][68];    // [k][batch row in tile]
    __shared__ float Bs[BK][132];   // [k][neuron row in tile]

    const int bm  = blockIdx.x;        // batch tile  0..3
    const int bn  = blockIdx.y;        // neuron tile 0..31 (128 cols each)
    const int seg = blockIdx.z;        // 0..15
    const int p   = seg & 7;           // panel index
    const int tid = (int)threadIdx.x;
    const int half = tid >> 8;         // 0: A-stager waves, 1: B-stager waves
    // A staging (half==0): row = (tid&255)>>2, k-slots {4g..4g+3},{16+4g..}
    const int srowA = (tid & 255) >> 2;
    const int sk4   = (tid & 3) * 4;
    // B staging (half==1): row = tid&127, h = (tid>>7)&1, k in [16h, 16h+16)
    const int srowB = tid & 127;
    const int kB    = ((tid >> 7) & 1) * 16;
    // micro-tile: rows ty*4..+3, cols tx*4..+3
    const int tx = tid & 31;
    const int ty = tid >> 5;

    const float* src;
    if (half == 0) {
        if (seg < 8)
            src = x    + ((size_t)(bm * 64 + srowA) * NT + (size_t)t) * ND + p * KC + sk4;
        else
            src = spkp + (size_t)(bm * 64 + srowA) * NL + p * KC + sk4;
    } else {
        if (seg < 8)
            src = W1   + (size_t)(bn * 128 + srowB) * ND + p * KC + kB;
        else
            src = Wr1  + (size_t)(bn * 128 + srowB) * NL + p * KC + kB;
    }

    float acc[4][4];
#pragma unroll
    for (int i = 0; i < 4; ++i)
#pragma unroll
        for (int j = 0; j < 4; ++j) acc[i][j] = 0.f;

    // prefetch slab 0
    float4 f0, f1, f2, f3;
    if (half == 0) {
        f0 = *(const float4*)(src);         // k = sk4 .. sk4+3
        f1 = *(const float4*)(src + 16);    // k = sk4+16 .. +19
    } else {
        f0 = *(const float4*)(src);         // k = kB .. kB+3
        f1 = *(const float4*)(src + 4);
        f2 = *(const float4*)(src + 8);
        f3 = *(const float4*)(src + 12);
    }

    const int NSLAB = KC / BK;   // 16
    for (int it = 0; it < NSLAB; ++it) {
        __syncthreads();   // previous iteration's LDS reads complete
        if (half == 0) {
            As[sk4 + 0][srowA] = f0.x;
            As[sk4 + 1][srowA] = f0.y;
            As[sk4 + 2][srowA] = f0.z;
            As[sk4 + 3][srowA] = f0.w;
            As[sk4 + 16][srowA] = f1.x;
            As[sk4 + 17][srowA] = f1.y;
            As[sk4 + 18][srowA] = f1.z;
            As[sk4 + 19][srowA] = f1.w;
        } else {
            Bs[kB + 0][srowB] = f0.x;
            Bs[kB + 1][srowB] = f0.y;
            Bs[kB + 2][srowB] = f0.z;
            Bs[kB + 3][srowB] = f0.w;
            Bs[kB + 4][srowB] = f1.x;
            Bs[kB + 5][srowB] = f1.y;
            Bs[kB + 6][srowB] = f1.z;
            Bs[kB + 7][srowB] = f1.w;
            Bs[kB + 8][srowB] = f2.x;
            Bs[kB + 9][srowB] = f2.y;
            Bs[kB + 10][srowB] = f2.z;
            Bs[kB + 11][srowB] = f2.w;
            Bs[kB + 12][srowB] = f3.x;
            Bs[kB + 13][srowB] = f3.y;
            Bs[kB + 14][srowB] = f3.z;
            Bs[kB + 15][srowB] = f3.w;
        }
        __syncthreads();
        if (it + 1 < NSLAB) {   // prefetch next slab into regs (hidden by compute)
            const float* s2 = src + (size_t)(it + 1) * BK;
            if (half == 0) {
                f0 = *(const float4*)(s2);
                f1 = *(const float4*)(s2 + 16);
            } else {
                f0 = *(const float4*)(s2);
                f1 = *(const float4*)(s2 + 4);
                f2 = *(const float4*)(s2 + 8);
                f3 = *(const float4*)(s2 + 12);
            }
        }
#pragma unroll
        for (int kk = 0; kk < BK; ++kk) {
            float a4[4], b4[4];
#pragma unroll
            for (int i = 0; i < 4; ++i) a4[i] = As[kk][ty * 4 + i];
#pragma unroll
            for (int j = 0; j < 4; ++j) b4[j] = Bs[kk][tx * 4 + j];
#pragma unroll
            for (int i = 0; i < 4; ++i)
#pragma unroll
                for (int j = 0; j < 4; ++j)
                    acc[i][j] = __fmaf_rn(a4[i], b4[j], acc[i][j]);
        }
    }

#pragma unroll
    for (int i = 0; i < 4; ++i) {
        const int row = bm * 64 + ty * 4 + i;
        float* crow = part + ((size_t)seg * NB + row) * NL + bn * 128 + tx * 4;
        *(float4*)crow = make_float4(acc[i][0], acc[i][1], acc[i][2], acc[i][3]);
    }
}

// ---------------- fused fold + membrane/spike + layer 2 ----------------------
// One block per batch row (proven r14-r24).
__global__ __launch_bounds__(256)
void snn_fold_l2(const float* __restrict__ part, const float* __restrict__ b1,
                 const float* __restrict__ br1, const float* __restrict__ spkp,
                 float* __restrict__ mem1, float* __restrict__ spkn,
                 const float* __restrict__ W2, const float* __restrict__ b2,
                 const float* __restrict__ Wr2, const float* __restrict__ br2,
                 float* __restrict__ mem2, float* __restrict__ spk2,
                 float* __restrict__ out, int t)
{
    __shared__ float s_spk[NL];
    __shared__ float s_red[NC][8];

    const int b = blockIdx.x;
    const int tid = (int)threadIdx.x;
    const size_t n4 = (size_t)NB * NL / 4;
    const float4* p4 = (const float4*)part;

#pragma unroll
    for (int u = 0; u < 4; ++u) {
        const int c4 = u * 256 + tid;
        const size_t i4 = (size_t)b * (NL / 4) + c4;

        float4 s[16];
#pragma unroll
        for (int s_i = 0; s_i < 16; ++s_i) s[s_i] = p4[(size_t)s_i * n4 + i4];

        float resW[4], resR[4];
        {
            const float* c = (const float*)&s[0];
            resW[0] = c[0]; resW[1] = c[1]; resW[2] = c[2]; resW[3] = c[3];
        }
#pragma unroll
        for (int s_i = 1; s_i < 8; ++s_i) {
            const float* c = (const float*)&s[s_i];
            resW[0] = __fadd_rn(resW[0], c[0]);
            resW[1] = __fadd_rn(resW[1], c[1]);
            resW[2] = __fadd_rn(resW[2], c[2]);
            resW[3] = __fadd_rn(resW[3], c[3]);
        }
        {
            const float* c = (const float*)&s[8];
            resR[0] = c[0]; resR[1] = c[1]; resR[2] = c[2]; resR[3] = c[3];
        }
#pragma unroll
        for (int s_i = 9; s_i < 16; ++s_i) {
            const float* c = (const float*)&s[s_i];
            resR[0] = __fadd_rn(resR[0], c[0]);
            resR[1] = __fadd_rn(resR[1], c[1]);
            resR[2] = __fadd_rn(resR[2], c[2]);
            resR[3] = __fadd_rn(resR[3], c[3]);
        }

        const float4 vb1 = ((const float4*)b1)[c4];
        const float4 vbr = ((const float4*)br1)[c4];
        const float4 vm  = ((const float4*)mem1)[i4];
        const float4 vsp = ((const float4*)spkp)[i4];
        const float bm[4]  = {vb1.x, vb1.y, vb1.z, vb1.w};
        const float brm[4] = {vbr.x, vbr.y, vbr.z, vbr.w};
        const float mm[4]  = {vm.x, vm.y, vm.z, vm.w};
        const float spm[4] = {vsp.x, vsp.y, vsp.z, vsp.w};

        float mo[4], so[4];
#pragma unroll
        for (int c = 0; c < 4; ++c) {
            const float cur1 = __fadd_rn(resW[c], bm[c]);
            float m = __fmul_rn(0.9f, mm[c]);
            m = __fadd_rn(m, cur1);
            m = __fadd_rn(m, resR[c]);
            m = __fadd_rn(m, brm[c]);
            m = __fsub_rn(m, __fmul_rn(spm[c], 1.0f));
            mo[c] = m;
            so[c] = (__fsub_rn(m, 1.0f) > 0.f) ? 1.0f : 0.0f;
        }
        ((float4*)mem1)[i4] = make_float4(mo[0], mo[1], mo[2], mo[3]);
        const float4 sv = make_float4(so[0], so[1], so[2], so[3]);
        ((float4*)spkn)[i4] = sv;
        *(float4*)(s_spk + c4 * 4) = sv;
    }
    __syncthreads();

    if (tid < NC * 8) {
        const int j = tid >> 3;
        const int p = tid & 7;
        const float* sp   = s_spk + p * KC;
        const float* wrow = W2 + (size_t)j * NL + p * KC;
        float a = 0.f;
        for (int k = 0; k < KC; ++k)
            a = __fmaf_rn(sp[k], wrow[k], a);
        s_red[j][p] = a;
    }
    __syncthreads();

    if (tid < NC) {
        const int j = tid;
        float spv[NC];
#pragma unroll
        for (int i = 0; i < NC; ++i) spv[i] = spk2[(size_t)b * NC + i];
        const float mprev = mem2[(size_t)b * NC + j];

        float carry = s_red[j][0];
#pragma unroll
        for (int p = 1; p < 8; ++p) carry = __fadd_rn(carry, s_red[j][p]);
        const float cur2 = __fadd_rn(carry, b2[j]);

        float rr = 0.f;
#pragma unroll
        for (int i = 0; i < NC; ++i)
            rr = __fmaf_rn(spv[i], Wr2[j * NC + i], rr);

        float m = __fmul_rn(0.9f, mprev);
        m = __fadd_rn(m, cur2);
        m = __fadd_rn(m, rr);
        m = __fadd_rn(m, br2[j]);
        m = __fsub_rn(m, __fmul_rn(spv[j], 1.0f));
        const float s = (__fsub_rn(m, 1.0f) > 0.f) ? 1.0f : 0.0f;

        mem2[(size_t)b * NC + j] = m;
        spk2[(size_t)b * NC + j] = s;
        const size_t o = (size_t)t * NB * NC + (size_t)b * NC + j;
        out[o] = s;                               // spk_rec  [T,B,NC]
        out[(size_t)NT * NB * NC + o] = m;        // mem_rec  [T,B,NC]
    }
}

extern "C" void kernel_launch(void* const* d_in, const int* in_sizes, int n_in,
                              void* d_out, int out_size, void* d_ws, size_t ws_size,
                              hipStream_t stream)
{
    const float* x   = (const float*)d_in[0];
    const float* W1  = (const float*)d_in[1];
    const float* b1  = (const float*)d_in[2];
    const float* Wr1 = (const float*)d_in[3];
    const float* br1 = (const float*)d_in[4];
    const float* W2  = (const float*)d_in[5];
    const float* b2  = (const float*)d_in[6];
    const float* Wr2 = (const float*)d_in[7];
    const float* br2 = (const float*)d_in[8];
    float* out = (float*)d_out;

    char* w = (char*)d_ws;
    const size_t MB = 1024 * 1024;
    float* part = (float*)(w);              // 64 MB [16][NB][NL] partials
    float* mem1 = (float*)(w + 64 * MB);    //  4 MB [NB, NL]
    float* spkA = (float*)(w + 68 * MB);    //  4 MB [NB, NL]
    float* spkB = (float*)(w + 72 * MB);    //  4 MB [NB, NL]
    float* mem2 = (float*)(w + 76 * MB);    // [NB, NC]
    float* spk2 = mem2 + (size_t)NB * NC;   // [NB, NC]

    snn_zero<<<dim3((NB * NL + 255) / 256), dim3(256), 0, stream>>>(
        mem1, spkA, mem2, spk2);

    for (int t = 0; t < NT; ++t) {
        const float* sp_in  = (t & 1) ? spkB : spkA;
        float*       sp_out = (t & 1) ? spkA : spkB;
        gemm_panel<<<dim3(4, 32, 16), dim3(512), 0, stream>>>(
            x, W1, Wr1, sp_in, part, t);
        snn_fold_l2<<<dim3(NB), dim3(256), 0, stream>>>(
            part, b1, br1, sp_in, mem1, sp_out,
            W2, b2, Wr2, br2, mem2, spk2, out, t);
    }
}

// Round 26
// 6752.758 us; speedup vs baseline: 1.1074x; 1.1074x over previous
//
#include <hip/hip_runtime.h>

#define NB 256
#define NT 32
#define ND 4096
#define NL 4096
#define NC 10
#define KC 512   // verified bit-exact: GEBP panels {512 x 8} per K=4096 matmul
#define BK 32    // k-slab per barrier pair; k-order within panel still ascending

// ---------------- state zero-init --------------------------------------------
__global__ void snn_zero(float* __restrict__ mem1, float* __restrict__ spkA,
                         float* __restrict__ mem2, float* __restrict__ spk2)
{
    const size_t i = (size_t)blockIdx.x * blockDim.x + threadIdx.x;
    if (i < (size_t)NB * NL) { mem1[i] = 0.f; spkA[i] = 0.f; }
    if (i < (size_t)NB * NC) { mem2[i] = 0.f; spk2[i] = 0.f; }
}

// ---------------- GEMM panel kernel (64x128 tile, 4x8 micro, BK=32) ----------
// Grid (4, 32, 16): bm = blockIdx.x, bn = blockIdx.y (128-col tiles), seg = z.
// seg 0..7  : panel p=seg   of x @ W1^T     (k in [512p, 512p+512))
// seg 8..15 : panel p=seg-8 of spkp @ Wr1^T
// Per output element: sequential ascending-k FMA chain from 0 (bit-exact).
// A-stage: r22's split-k pattern (2-way bank writes). B-stage: row-per-thread,
// 16 b32 writes at bank (4i+row)%32 -> 2 lanes/bank (free). B-reads split at
// tx*4 / 64+tx*4 (2-way, free). 32 FMA per 3 ds_read_b128.
__global__ __launch_bounds__(256)
void gemm_panel(const float* __restrict__ x, const float* __restrict__ W1,
                const float* __restrict__ Wr1, const float* __restrict__ spkp,
                float* __restrict__ part, int t)
{
    __shared__ float As[BK][68];    // [k][batch row in tile]
    __shared__ float Bs[BK][132];   // [k][neuron row in tile]

    const int bm  = blockIdx.x;        // batch tile  0..3
    const int bn  = blockIdx.y;        // neuron tile 0..31 (128 cols each)
    const int seg = blockIdx.z;        // 0..15
    const int p   = seg & 7;           // panel index
    const int tid = (int)threadIdx.x;
    // A staging: row = tid>>2 (0..63), g = tid&3, k-slots {4g..4g+3},{16+4g..}
    const int srowA = tid >> 2;
    const int sk4   = (tid & 3) * 4;
    // B staging: row = tid&127 (0..127), h = tid>>7 (0..1), k in [16h, 16h+16)
    const int srowB = tid & 127;
    const int kB    = (tid >> 7) * 16;
    // micro-tile: rows ty*4..+3, cols tx*4..+3 and 64+tx*4..+3
    const int tx = tid & 15;
    const int ty = tid >> 4;

    const float* Asrc;
    const float* Bsrc;
    if (seg < 8) {
        Asrc = x   + ((size_t)(bm * 64 + srowA) * NT + (size_t)t) * ND + p * KC + sk4;
        Bsrc = W1  +  (size_t)(bn * 128 + srowB) * ND + p * KC + kB;
    } else {
        Asrc = spkp + (size_t)(bm * 64 + srowA) * NL + p * KC + sk4;
        Bsrc = Wr1  + (size_t)(bn * 128 + srowB) * NL + p * KC + kB;
    }

    float acc[4][8];
#pragma unroll
    for (int i = 0; i < 4; ++i)
#pragma unroll
        for (int j = 0; j < 8; ++j) acc[i][j] = 0.f;

    // prefetch slab 0
    float4 av0 = *(const float4*)(Asrc);        // k = sk4 .. sk4+3
    float4 av1 = *(const float4*)(Asrc + 16);   // k = sk4+16 .. +19
    float4 bw0 = *(const float4*)(Bsrc);        // k = kB .. kB+3
    float4 bw1 = *(const float4*)(Bsrc + 4);
    float4 bw2 = *(const float4*)(Bsrc + 8);
    float4 bw3 = *(const float4*)(Bsrc + 12);

    const int NSLAB = KC / BK;   // 16
    for (int it = 0; it < NSLAB; ++it) {
        __syncthreads();   // previous iteration's LDS reads complete
        As[sk4 + 0][srowA] = av0.x;
        As[sk4 + 1][srowA] = av0.y;
        As[sk4 + 2][srowA] = av0.z;
        As[sk4 + 3][srowA] = av0.w;
        As[sk4 + 16][srowA] = av1.x;
        As[sk4 + 17][srowA] = av1.y;
        As[sk4 + 18][srowA] = av1.z;
        As[sk4 + 19][srowA] = av1.w;
        Bs[kB + 0][srowB] = bw0.x;
        Bs[kB + 1][srowB] = bw0.y;
        Bs[kB + 2][srowB] = bw0.z;
        Bs[kB + 3][srowB] = bw0.w;
        Bs[kB + 4][srowB] = bw1.x;
        Bs[kB + 5][srowB] = bw1.y;
        Bs[kB + 6][srowB] = bw1.z;
        Bs[kB + 7][srowB] = bw1.w;
        Bs[kB + 8][srowB] = bw2.x;
        Bs[kB + 9][srowB] = bw2.y;
        Bs[kB + 10][srowB] = bw2.z;
        Bs[kB + 11][srowB] = bw2.w;
        Bs[kB + 12][srowB] = bw3.x;
        Bs[kB + 13][srowB] = bw3.y;
        Bs[kB + 14][srowB] = bw3.z;
        Bs[kB + 15][srowB] = bw3.w;
        __syncthreads();
        if (it + 1 < NSLAB) {   // prefetch next slab into regs (hidden by compute)
            const float* a2 = Asrc + (size_t)(it + 1) * BK;
            const float* b2 = Bsrc + (size_t)(it + 1) * BK;
            av0 = *(const float4*)(a2);
            av1 = *(const float4*)(a2 + 16);
            bw0 = *(const float4*)(b2);
            bw1 = *(const float4*)(b2 + 4);
            bw2 = *(const float4*)(b2 + 8);
            bw3 = *(const float4*)(b2 + 12);
        }
#pragma unroll
        for (int kk = 0; kk < BK; ++kk) {
            float a4[4], b8[8];
#pragma unroll
            for (int i = 0; i < 4; ++i) a4[i] = As[kk][ty * 4 + i];
#pragma unroll
            for (int j = 0; j < 4; ++j) b8[j] = Bs[kk][tx * 4 + j];
#pragma unroll
            for (int j = 0; j < 4; ++j) b8[4 + j] = Bs[kk][64 + tx * 4 + j];
#pragma unroll
            for (int i = 0; i < 4; ++i)
#pragma unroll
                for (int j = 0; j < 8; ++j)
                    acc[i][j] = __fmaf_rn(a4[i], b8[j], acc[i][j]);
        }
    }

#pragma unroll
    for (int i = 0; i < 4; ++i) {
        const int row = bm * 64 + ty * 4 + i;
        float* crow = part + ((size_t)seg * NB + row) * NL + bn * 128;
        *(float4*)(crow + tx * 4)      = make_float4(acc[i][0], acc[i][1],
                                                     acc[i][2], acc[i][3]);
        *(float4*)(crow + 64 + tx * 4) = make_float4(acc[i][4], acc[i][5],
                                                     acc[i][6], acc[i][7]);
    }
}

// ---------------- fused fold + membrane/spike + layer 2 ----------------------
// One block per batch row (proven r14-r25).
__global__ __launch_bounds__(256)
void snn_fold_l2(const float* __restrict__ part, const float* __restrict__ b1,
                 const float* __restrict__ br1, const float* __restrict__ spkp,
                 float* __restrict__ mem1, float* __restrict__ spkn,
                 const float* __restrict__ W2, const float* __restrict__ b2,
                 const float* __restrict__ Wr2, const float* __restrict__ br2,
                 float* __restrict__ mem2, float* __restrict__ spk2,
                 float* __restrict__ out, int t)
{
    __shared__ float s_spk[NL];
    __shared__ float s_red[NC][8];

    const int b = blockIdx.x;
    const int tid = (int)threadIdx.x;
    const size_t n4 = (size_t)NB * NL / 4;
    const float4* p4 = (const float4*)part;

#pragma unroll
    for (int u = 0; u < 4; ++u) {
        const int c4 = u * 256 + tid;
        const size_t i4 = (size_t)b * (NL / 4) + c4;

        float4 s[16];
#pragma unroll
        for (int s_i = 0; s_i < 16; ++s_i) s[s_i] = p4[(size_t)s_i * n4 + i4];

        float resW[4], resR[4];
        {
            const float* c = (const float*)&s[0];
            resW[0] = c[0]; resW[1] = c[1]; resW[2] = c[2]; resW[3] = c[3];
        }
#pragma unroll
        for (int s_i = 1; s_i < 8; ++s_i) {
            const float* c = (const float*)&s[s_i];
            resW[0] = __fadd_rn(resW[0], c[0]);
            resW[1] = __fadd_rn(resW[1], c[1]);
            resW[2] = __fadd_rn(resW[2], c[2]);
            resW[3] = __fadd_rn(resW[3], c[3]);
        }
        {
            const float* c = (const float*)&s[8];
            resR[0] = c[0]; resR[1] = c[1]; resR[2] = c[2]; resR[3] = c[3];
        }
#pragma unroll
        for (int s_i = 9; s_i < 16; ++s_i) {
            const float* c = (const float*)&s[s_i];
            resR[0] = __fadd_rn(resR[0], c[0]);
            resR[1] = __fadd_rn(resR[1], c[1]);
            resR[2] = __fadd_rn(resR[2], c[2]);
            resR[3] = __fadd_rn(resR[3], c[3]);
        }

        const float4 vb1 = ((const float4*)b1)[c4];
        const float4 vbr = ((const float4*)br1)[c4];
        const float4 vm  = ((const float4*)mem1)[i4];
        const float4 vsp = ((const float4*)spkp)[i4];
        const float bm[4]  = {vb1.x, vb1.y, vb1.z, vb1.w};
        const float brm[4] = {vbr.x, vbr.y, vbr.z, vbr.w};
        const float mm[4]  = {vm.x, vm.y, vm.z, vm.w};
        const float spm[4] = {vsp.x, vsp.y, vsp.z, vsp.w};

        float mo[4], so[4];
#pragma unroll
        for (int c = 0; c < 4; ++c) {
            const float cur1 = __fadd_rn(resW[c], bm[c]);
            float m = __fmul_rn(0.9f, mm[c]);
            m = __fadd_rn(m, cur1);
            m = __fadd_rn(m, resR[c]);
            m = __fadd_rn(m, brm[c]);
            m = __fsub_rn(m, __fmul_rn(spm[c], 1.0f));
            mo[c] = m;
            so[c] = (__fsub_rn(m, 1.0f) > 0.f) ? 1.0f : 0.0f;
        }
        ((float4*)mem1)[i4] = make_float4(mo[0], mo[1], mo[2], mo[3]);
        const float4 sv = make_float4(so[0], so[1], so[2], so[3]);
        ((float4*)spkn)[i4] = sv;
        *(float4*)(s_spk + c4 * 4) = sv;
    }
    __syncthreads();

    if (tid < NC * 8) {
        const int j = tid >> 3;
        const int p = tid & 7;
        const float* sp   = s_spk + p * KC;
        const float* wrow = W2 + (size_t)j * NL + p * KC;
        float a = 0.f;
        for (int k = 0; k < KC; ++k)
            a = __fmaf_rn(sp[k], wrow[k], a);
        s_red[j][p] = a;
    }
    __syncthreads();

    if (tid < NC) {
        const int j = tid;
        float spv[NC];
#pragma unroll
        for (int i = 0; i < NC; ++i) spv[i] = spk2[(size_t)b * NC + i];
        const float mprev = mem2[(size_t)b * NC + j];

        float carry = s_red[j][0];
#pragma unroll
        for (int p = 1; p < 8; ++p) carry = __fadd_rn(carry, s_red[j][p]);
        const float cur2 = __fadd_rn(carry, b2[j]);

        float rr = 0.f;
#pragma unroll
        for (int i = 0; i < NC; ++i)
            rr = __fmaf_rn(spv[i], Wr2[j * NC + i], rr);

        float m = __fmul_rn(0.9f, mprev);
        m = __fadd_rn(m, cur2);
        m = __fadd_rn(m, rr);
        m = __fadd_rn(m, br2[j]);
        m = __fsub_rn(m, __fmul_rn(spv[j], 1.0f));
        const float s = (__fsub_rn(m, 1.0f) > 0.f) ? 1.0f : 0.0f;

        mem2[(size_t)b * NC + j] = m;
        spk2[(size_t)b * NC + j] = s;
        const size_t o = (size_t)t * NB * NC + (size_t)b * NC + j;
        out[o] = s;                               // spk_rec  [T,B,NC]
        out[(size_t)NT * NB * NC + o] = m;        // mem_rec  [T,B,NC]
    }
}

extern "C" void kernel_launch(void* const* d_in, const int* in_sizes, int n_in,
                              void* d_out, int out_size, void* d_ws, size_t ws_size,
                              hipStream_t stream)
{
    const float* x   = (const float*)d_in[0];
    const float* W1  = (const float*)d_in[1];
    const float* b1  = (const float*)d_in[2];
    const float* Wr1 = (const float*)d_in[3];
    const float* br1 = (const float*)d_in[4];
    const float* W2  = (const float*)d_in[5];
    const float* b2  = (const float*)d_in[6];
    const float* Wr2 = (const float*)d_in[7];
    const float* br2 = (const float*)d_in[8];
    float* out = (float*)d_out;

    char* w = (char*)d_ws;
    const size_t MB = 1024 * 1024;
    float* part = (float*)(w);              // 64 MB [16][NB][NL] partials
    float* mem1 = (float*)(w + 64 * MB);    //  4 MB [NB, NL]
    float* spkA = (float*)(w + 68 * MB);    //  4 MB [NB, NL]
    float* spkB = (float*)(w + 72 * MB);    //  4 MB [NB, NL]
    float* mem2 = (float*)(w + 76 * MB);    // [NB, NC]
    float* spk2 = mem2 + (size_t)NB * NC;   // [NB, NC]

    snn_zero<<<dim3((NB * NL + 255) / 256), dim3(256), 0, stream>>>(
        mem1, spkA, mem2, spk2);

    for (int t = 0; t < NT; ++t) {
        const float* sp_in  = (t & 1) ? spkB : spkA;
        float*       sp_out = (t & 1) ? spkA : spkB;
        gemm_panel<<<dim3(4, 32, 16), dim3(256), 0, stream>>>(
            x, W1, Wr1, sp_in, part, t);
        snn_fold_l2<<<dim3(NB), dim3(256), 0, stream>>>(
            part, b1, br1, sp_in, mem1, sp_out,
            W2, b2, Wr2, br2, mem2, spk2, out, t);
    }
}